// Round 8
// baseline (173.555 us; speedup 1.0000x reference)
//
#include <hip/hip_runtime.h>

#define NNODES 25000
#define NEDGES 400000
#define EPB 32            // items per block (pre kernel)
#define XSTR2 68
#define EPSF 1e-6f
#define RSQRT2 0.7071067811865476f

// ======================= Cl(3,0) tables, blade order [1,e1,e2,e3,e12,e13,e23,e123] ==========
static constexpr int GJ[64] = {
 0,1,2,3,4,5,6,7,
 1,0,4,5,2,3,7,6,
 2,4,0,6,1,7,3,5,
 3,5,6,0,7,1,2,4,
 4,2,1,7,0,6,5,3,
 5,3,7,1,6,0,4,2,
 6,7,3,2,5,4,0,1,
 7,6,5,4,3,2,1,0};
static constexpr int GS[64] = {
 1, 1, 1, 1, 1, 1, 1, 1,
 1, 1, 1, 1, 1, 1, 1, 1,
 1,-1, 1, 1,-1,-1, 1,-1,
 1,-1,-1, 1, 1,-1,-1, 1,
 1,-1, 1, 1,-1,-1, 1,-1,
 1,-1,-1, 1, 1,-1,-1, 1,
 1, 1,-1, 1,-1, 1,-1,-1,
 1, 1,-1, 1,-1, 1,-1,-1};
static constexpr int GP[64] = {
  0, 1, 1, 1, 2, 2, 2, 3,
  5, 4, 7, 7, 6, 6, 9, 8,
  5, 7, 4, 7, 6, 9, 6, 8,
  5, 7, 7, 4, 9, 6, 6, 8,
 13,11,11,15,10,14,14,12,
 13,11,15,11,14,10,14,12,
 13,15,11,11,14,14,10,12,
 19,18,18,18,17,17,17,16};

struct WP {
  const float *wlin, *blin, *asi, *bsi, *wr, *wg, *wl, *bl, *an, *aln;
};

__device__ __forceinline__ float sigm(float x) {
  return __builtin_amdgcn_rcpf(1.f + __expf(-x));
}
__device__ __forceinline__ float frcp(float x) { return __builtin_amdgcn_rcpf(x); }
__device__ __forceinline__ float fsqrt(float x) { return __builtin_amdgcn_sqrtf(x); }

// intra-wave LDS fence (all cross-lane X sharing is within one wave64)
__device__ __forceinline__ void wave_fence() {
  asm volatile("s_waitcnt lgkmcnt(0)" ::: "memory");
  __builtin_amdgcn_sched_barrier(0);
}

// ======================= tail weight layout (relative to a base pointer) =================
#define C_WR   0                  // [8] stride 36
#define C_WL   (C_WR + 288)
#define C_WG   (C_WL + 288)       // [8][20]
#define C_BLIN (C_WG + 160)
#define C_ASI  (C_BLIN + 8)
#define C_BSI  (C_ASI + 32)
#define C_BL   (C_BSI + 32)
#define C_AN   (C_BL + 8)
#define C_ALN  (C_AN + 32)
#define C_TOT  (C_ALN + 8)        // 856
#define C_WLIN C_TOT              // node/fallback: [8][16][4] stride 68
#define CN_TOT (C_WLIN + 8*68)    // 1400

__device__ __forceinline__ void stage_common(int tid, float* Ws, const WP& wp) {
  int t = tid;
  if (t < 256) Ws[C_WR + (t >> 5) * 36 + (t & 31)] = wp.wr[t];
  if (t < 256) Ws[C_WL + (t >> 5) * 36 + (t & 31)] = wp.wl[t];
  if (t < 160) Ws[C_WG + t] = wp.wg[t];
  if (t < 8)   Ws[C_BLIN + t] = wp.blin[t];
  if (t < 32)  Ws[C_ASI + t] = wp.asi[t];
  if (t < 32)  Ws[C_BSI + t] = wp.bsi[t];
  if (t < 8)   Ws[C_BL + t]  = wp.bl[t];
  if (t < 32)  Ws[C_AN + t]  = wp.an[t];
  if (t < 8)   Ws[C_ALN + t] = wp.aln[t];
}

// silu -> s -> right-linear+norm -> geo -> left-linear -> LN (8 lanes of one group share X)
__device__ __forceinline__ void clifford_tail(float* __restrict__ X,
                                              const float* __restrict__ Ws,
                                              int n, const float* y, float* z)
{
  const float q1 = y[1]*y[1] + y[2]*y[2] + y[3]*y[3];
  const float q2 = y[4]*y[4] + y[5]*y[5] + y[6]*y[6];
  const float q3 = y[7]*y[7];
  const float g0 = sigm(Ws[C_ASI + n*4 + 0] * y[0] + Ws[C_BSI + n*4 + 0]);
  const float g1 = sigm(Ws[C_ASI + n*4 + 1] * q1  + Ws[C_BSI + n*4 + 1]);
  const float g2 = sigm(Ws[C_ASI + n*4 + 2] * q2  + Ws[C_BSI + n*4 + 2]);
  const float g3 = sigm(Ws[C_ASI + n*4 + 3] * q3  + Ws[C_BSI + n*4 + 3]);
  float s[8] = { g0*y[0], g1*y[1], g1*y[2], g1*y[3],
                 g2*y[4], g2*y[5], g2*y[6], g3*y[7] };
  *(float4*)&X[n*8]     = make_float4(s[0], s[1], s[2], s[3]);
  *(float4*)&X[n*8 + 4] = make_float4(s[4], s[5], s[6], s[7]);
  wave_fence();

  float xr[8], zl[8];
  #pragma unroll
  for (int i = 0; i < 8; ++i) { xr[i] = 0.f; zl[i] = 0.f; }
  #pragma unroll
  for (int m = 0; m < 8; ++m) {
    const float4 wr4 = *(const float4*)&Ws[C_WR + n * 36 + m * 4];
    const float4 wl4 = *(const float4*)&Ws[C_WL + n * 36 + m * 4];
    const float4 xa = *(const float4*)&X[m * 8];
    const float4 xb = *(const float4*)&X[m * 8 + 4];
    xr[0]=fmaf(xa.x,wr4.x,xr[0]); xr[1]=fmaf(xa.y,wr4.y,xr[1]); xr[2]=fmaf(xa.z,wr4.y,xr[2]); xr[3]=fmaf(xa.w,wr4.y,xr[3]);
    xr[4]=fmaf(xb.x,wr4.z,xr[4]); xr[5]=fmaf(xb.y,wr4.z,xr[5]); xr[6]=fmaf(xb.z,wr4.z,xr[6]); xr[7]=fmaf(xb.w,wr4.w,xr[7]);
    zl[0]=fmaf(xa.x,wl4.x,zl[0]); zl[1]=fmaf(xa.y,wl4.y,zl[1]); zl[2]=fmaf(xa.z,wl4.y,zl[2]); zl[3]=fmaf(xa.w,wl4.y,zl[3]);
    zl[4]=fmaf(xb.x,wl4.z,zl[4]); zl[5]=fmaf(xb.y,wl4.z,zl[5]); zl[6]=fmaf(xb.z,wl4.z,zl[6]); zl[7]=fmaf(xb.w,wl4.w,zl[7]);
  }
  zl[0] += Ws[C_BL + n];

  {
    const float t0 = fabsf(xr[0]);
    const float t1 = fsqrt(xr[1]*xr[1] + xr[2]*xr[2] + xr[3]*xr[3]);
    const float t2 = fsqrt(xr[4]*xr[4] + xr[5]*xr[5] + xr[6]*xr[6]);
    const float t3 = fabsf(xr[7]);
    const float d0 = frcp(sigm(Ws[C_AN + n*4 + 0]) * (t0 - 1.f) + 1.f + EPSF);
    const float d1 = frcp(sigm(Ws[C_AN + n*4 + 1]) * (t1 - 1.f) + 1.f + EPSF);
    const float d2 = frcp(sigm(Ws[C_AN + n*4 + 2]) * (t2 - 1.f) + 1.f + EPSF);
    const float d3 = frcp(sigm(Ws[C_AN + n*4 + 3]) * (t3 - 1.f) + 1.f + EPSF);
    xr[0] *= d0; xr[1] *= d1; xr[2] *= d1; xr[3] *= d1;
    xr[4] *= d2; xr[5] *= d2; xr[6] *= d2; xr[7] *= d3;
  }

  float geo[8];
  #pragma unroll
  for (int i = 0; i < 8; ++i) geo[i] = 0.f;
  {
    const int wgb = C_WG + n * 20;
    #pragma unroll
    for (int i = 0; i < 8; ++i) {
      #pragma unroll
      for (int k = 0; k < 8; ++k) {
        const float t = s[i] * xr[k];
        const float w = Ws[wgb + GP[i * 8 + k]];
        geo[GJ[i * 8 + k]] = fmaf(GS[i * 8 + k] > 0 ? w : -w, t, geo[GJ[i * 8 + k]]);
      }
    }
  }

  #pragma unroll
  for (int i = 0; i < 8; ++i) z[i] = (zl[i] + geo[i]) * RSQRT2;

  float sq = 0.f;
  #pragma unroll
  for (int i = 0; i < 8; ++i) sq = fmaf(z[i], z[i], sq);
  float nr = fsqrt(sq);
  nr += __shfl_xor(nr, 1);
  nr += __shfl_xor(nr, 2);
  nr += __shfl_xor(nr, 4);
  const float scale = Ws[C_ALN + n] * frcp(nr * 0.125f + EPSF);
  #pragma unroll
  for (int i = 0; i < 8; ++i) z[i] *= scale;
}

// ======================= fast single-block scan (2 barriers, alias-safe) ================
__global__ __launch_bounds__(1024)
void csr_scan_fast(const int* __restrict__ deg, int* __restrict__ ptr,
                   int* __restrict__ fill)
{
  __shared__ int wsum[16];
  const int t = threadIdx.x;
  const int base = t * 32;
  int d[32];
  int s = 0;
  #pragma unroll
  for (int i = 0; i < 8; ++i) {
    int idx = base + i * 4;
    int4 v = make_int4(0, 0, 0, 0);
    if (idx + 3 < NNODES) v = *(const int4*)(deg + idx);
    else {
      if (idx + 0 < NNODES) v.x = deg[idx + 0];
      if (idx + 1 < NNODES) v.y = deg[idx + 1];
      if (idx + 2 < NNODES) v.z = deg[idx + 2];
    }
    d[i*4+0] = v.x; d[i*4+1] = v.y; d[i*4+2] = v.z; d[i*4+3] = v.w;
    s += v.x + v.y + v.z + v.w;
  }
  const int lane = t & 63;
  int incl = s;
  #pragma unroll
  for (int off = 1; off < 64; off <<= 1) {
    int u = __shfl_up(incl, off);
    if (lane >= off) incl += u;
  }
  const int wv = t >> 6;
  if (lane == 63) wsum[wv] = incl;
  __syncthreads();
  if (t < 16) {
    int v = wsum[t];
    int inc = v;
    #pragma unroll
    for (int off = 1; off < 16; off <<= 1) {
      int u = __shfl_up(inc, off);
      if (t >= off) inc += u;
    }
    wsum[t] = inc - v;       // exclusive wave offset
  }
  __syncthreads();
  int run = wsum[wv] + (incl - s);   // exclusive prefix of this thread's chunk
  #pragma unroll
  for (int i = 0; i < 8; ++i) {
    int idx = base + i * 4;
    int4 pv;
    pv.x = run; run += d[i*4+0];
    pv.y = run; run += d[i*4+1];
    pv.z = run; run += d[i*4+2];
    pv.w = run; run += d[i*4+3];
    if (idx + 3 < NNODES) {
      *(int4*)(ptr + idx)  = pv;
      *(int4*)(fill + idx) = pv;
    } else {
      if (idx + 0 < NNODES) { ptr[idx+0] = pv.x; fill[idx+0] = pv.x; }
      if (idx + 1 < NNODES) { ptr[idx+1] = pv.y; fill[idx+1] = pv.y; }
      if (idx + 2 < NNODES) { ptr[idx+2] = pv.z; fill[idx+2] = pv.z; }
    }
  }
  if (t == 1023) ptr[NNODES] = NEDGES;
}

// ======================= merged precompute(ue,ve) + degree count =======================
#define PRE_BLOCKS ((NNODES + EPB - 1) / EPB)   // 782
#define CNT_BLOCKS ((NEDGES + 255) / 256)       // 1563

__global__ __launch_bounds__(256)
void pre_count(const float* __restrict__ h,
               const float* __restrict__ wle,   // edge wlin [8][16][4]
               float* __restrict__ ue, float* __restrict__ ve,
               const int* __restrict__ eidx, int* __restrict__ deg)
{
  __shared__ __align__(16) float We[8 * 68];
  __shared__ __align__(16) float Xs[EPB * XSTR2];
  const int tid = threadIdx.x;

  if (blockIdx.x >= PRE_BLOCKS) {
    int e = (blockIdx.x - PRE_BLOCKS) * 256 + tid;
    if (e < NEDGES) atomicAdd(&deg[eidx[e]], 1);
    return;
  }

  for (int t = tid; t < 512; t += 256) We[(t >> 6) * 68 + (t & 63)] = wle[t];
  const int el = tid >> 3, n = tid & 7;
  const int item = blockIdx.x * EPB + el;
  float* X = &Xs[el * XSTR2];
  const bool act = item < NNODES;
  if (act) {
    const float4* ph = (const float4*)(h + (size_t)item * 64 + n * 8);
    *(float4*)&X[n * 8]     = ph[0];
    *(float4*)&X[n * 8 + 4] = ph[1];
  }
  __syncthreads();
  if (!act) return;
  float ua[8], va[8];
  #pragma unroll
  for (int i = 0; i < 8; ++i) { ua[i] = 0.f; va[i] = 0.f; }
  #pragma unroll
  for (int m = 0; m < 8; ++m) {
    const float4 xa = *(const float4*)&X[m * 8];
    const float4 xb = *(const float4*)&X[m * 8 + 4];
    const float4 wa = *(const float4*)&We[n * 68 + m * 4];
    const float4 wb = *(const float4*)&We[n * 68 + (m + 8) * 4];
    ua[0]=fmaf(xa.x,wa.x,ua[0]); ua[1]=fmaf(xa.y,wa.y,ua[1]); ua[2]=fmaf(xa.z,wa.y,ua[2]); ua[3]=fmaf(xa.w,wa.y,ua[3]);
    ua[4]=fmaf(xb.x,wa.z,ua[4]); ua[5]=fmaf(xb.y,wa.z,ua[5]); ua[6]=fmaf(xb.z,wa.z,ua[6]); ua[7]=fmaf(xb.w,wa.w,ua[7]);
    va[0]=fmaf(xa.x,wb.x,va[0]); va[1]=fmaf(xa.y,wb.y,va[1]); va[2]=fmaf(xa.z,wb.y,va[2]); va[3]=fmaf(xa.w,wb.y,va[3]);
    va[4]=fmaf(xb.x,wb.z,va[4]); va[5]=fmaf(xb.y,wb.z,va[5]); va[6]=fmaf(xb.z,wb.z,va[6]); va[7]=fmaf(xb.w,wb.w,va[7]);
  }
  float4* pu = (float4*)(ue + (size_t)item * 64 + n * 8);
  pu[0] = make_float4(ua[0],ua[1],ua[2],ua[3]); pu[1] = make_float4(ua[4],ua[5],ua[6],ua[7]);
  float4* pv = (float4*)(ve + (size_t)item * 64 + n * 8);
  pv[0] = make_float4(va[0],va[1],va[2],va[3]); pv[1] = make_float4(va[4],va[5],va[6],va[7]);
}

// ======================= scatter col indices into CSR order =======================
__global__ __launch_bounds__(256) void csr_scatter_cols(const int* __restrict__ eidx,
                                                        int* __restrict__ fill,
                                                        int* __restrict__ cols) {
  int e = blockIdx.x * 256 + threadIdx.x;
  if (e < NEDGES) {
    const int r = eidx[e];
    const int c = eidx[NEDGES + e];
    int pos = atomicAdd(&fill[r], 1);
    cols[pos] = c;
  }
}

// ======================= fused edge+node kernel: one wave64 per node ====================
// Wave = node. 8 groups of 8 lanes; per round each group processes one edge:
// gather ve[cols[p]], tail(ue[nid]+ve[c]) -> z, accumulate. Then cross-group reduce
// and slot-0 group runs the node block. No message buffer.
#define NPB 4   // nodes (waves) per 256-thread block
__global__ __launch_bounds__(256)
void cgenn6_fused(const float* __restrict__ h,
                  const float* __restrict__ ue, const float* __restrict__ ve,
                  const int* __restrict__ ptr, const int* __restrict__ cols,
                  float* __restrict__ out, WP we, WP wn)
{
  __shared__ __align__(16) float Ws[C_TOT + CN_TOT];  // [0,856) edge tail; [856,...) node
  __shared__ __align__(16) float Xe[NPB * 8 * 68];    // per (wave,slot) edge scratch
  __shared__ __align__(16) float Xn[NPB * 132];       // per wave node scratch
  const int tid  = threadIdx.x;
  const int wv   = tid >> 6;          // wave (node) slot in block
  const int slot = (tid >> 3) & 7;    // edge group within wave
  const int n    = tid & 7;           // channel
  const int nid  = blockIdx.x * NPB + wv;

  stage_common(tid, Ws, we);              // edge tail weights at base 0
  stage_common(tid, Ws + C_TOT, wn);      // node tail weights
  for (int t = tid; t < 512; t += 256)
    Ws[C_TOT + C_WLIN + (t >> 6) * 68 + (t & 63)] = wn.wlin[t];

  const int beg = ptr[nid], end = ptr[nid + 1];

  // each lane holds its channel-row of ue[nid] (same across slots -> L1 broadcast)
  const float4* pu = (const float4*)(ue + (size_t)nid * 64 + n * 8);
  const float4 u0 = pu[0], u1 = pu[1];

  __syncthreads();   // weights staged

  const float eb = Ws[C_BLIN + n];
  float* Xg = &Xe[(wv * 8 + slot) * 68];

  float a[8];
  #pragma unroll
  for (int i = 0; i < 8; ++i) a[i] = 0.f;

  const int rounds = (end - beg + 7) >> 3;
  for (int rd = 0; rd < rounds; ++rd) {
    const int p = beg + rd * 8 + slot;
    const bool act = (p < end);                 // uniform within the 8-lane group
    float4 v0 = make_float4(0.f, 0.f, 0.f, 0.f);
    float4 v1 = v0;
    if (act) {
      const int c = cols[p];
      const float4* pv = (const float4*)(ve + (size_t)c * 64 + n * 8);
      v0 = pv[0]; v1 = pv[1];
    }
    float y[8] = { u0.x+v0.x + eb, u0.y+v0.y, u0.z+v0.z, u0.w+v0.w,
                   u1.x+v1.x, u1.y+v1.y, u1.z+v1.z, u1.w+v1.w };
    float z[8];
    clifford_tail(Xg, Ws, n, y, z);             // uniform path (fence runs on all lanes)
    if (act) {
      #pragma unroll
      for (int i = 0; i < 8; ++i) a[i] += z[i];
    }
  }

  // cross-group reduce (lanes n, n+8, ..., n+56)
  #pragma unroll
  for (int i = 0; i < 8; ++i) {
    a[i] += __shfl_xor(a[i], 8);
    a[i] += __shfl_xor(a[i], 16);
    a[i] += __shfl_xor(a[i], 32);
  }

  if (slot == 0) {
    const float* Wn = Ws + C_TOT;
    float* X = &Xn[wv * 132];
    float hr[8];
    const float4* ph = (const float4*)(h + (size_t)nid * 64 + n * 8);
    const float4 h0 = ph[0], h1 = ph[1];
    hr[0]=h0.x; hr[1]=h0.y; hr[2]=h0.z; hr[3]=h0.w;
    hr[4]=h1.x; hr[5]=h1.y; hr[6]=h1.z; hr[7]=h1.w;
    *(float4*)&X[n*8]         = h0;
    *(float4*)&X[n*8 + 4]     = h1;
    *(float4*)&X[(8+n)*8]     = make_float4(a[0], a[1], a[2], a[3]);
    *(float4*)&X[(8+n)*8 + 4] = make_float4(a[4], a[5], a[6], a[7]);
    wave_fence();

    // full 16->8 mv_linear (node)
    float y[8];
    #pragma unroll
    for (int i = 0; i < 8; ++i) y[i] = 0.f;
    #pragma unroll
    for (int m = 0; m < 16; ++m) {
      const float4 w4 = *(const float4*)&Wn[C_WLIN + n * 68 + m * 4];
      const float4 xa = *(const float4*)&X[m * 8];
      const float4 xb = *(const float4*)&X[m * 8 + 4];
      y[0]=fmaf(xa.x,w4.x,y[0]); y[1]=fmaf(xa.y,w4.y,y[1]); y[2]=fmaf(xa.z,w4.y,y[2]); y[3]=fmaf(xa.w,w4.y,y[3]);
      y[4]=fmaf(xb.x,w4.z,y[4]); y[5]=fmaf(xb.y,w4.z,y[5]); y[6]=fmaf(xb.z,w4.z,y[6]); y[7]=fmaf(xb.w,w4.w,y[7]);
    }
    y[0] += Wn[C_BLIN + n];

    float z[8];
    clifford_tail(X, Wn, n, y, z);

    float4* po = (float4*)(out + (size_t)nid * 64 + n * 8);
    po[0] = make_float4(hr[0]+z[0], hr[1]+z[1], hr[2]+z[2], hr[3]+z[3]);
    po[1] = make_float4(hr[4]+z[4], hr[5]+z[5], hr[6]+z[6], hr[7]+z[7]);
  }
}

// ======================= MODE0 fallback (atomic path) ================
template<bool IS_NODE>
__global__ __launch_bounds__(256)
void cgenn_block(const float* __restrict__ h,
                 const int* __restrict__ eidx,
                 float* agg_out, WP wp)
{
  __shared__ __align__(16) float Ws[CN_TOT];
  __shared__ __align__(16) float Xs[EPB * 132];
  const int tid = threadIdx.x;
  stage_common(tid, Ws, wp);
  for (int t = tid; t < 512; t += 256)
    Ws[C_WLIN + (t >> 6) * 68 + (t & 63)] = wp.wlin[t];
  const int el = tid >> 3;
  const int n  = tid & 7;
  const int item = blockIdx.x * EPB + el;
  float* X = &Xs[el * 132];
  bool active = true;
  int r = 0;
  float hr[8];
  if (IS_NODE) {
    active = (item < NNODES);
    if (active) {
      const float4* ph = (const float4*)(h + (size_t)item * 64 + n * 8);
      float4 a0 = ph[0], a1 = ph[1];
      hr[0]=a0.x; hr[1]=a0.y; hr[2]=a0.z; hr[3]=a0.w;
      hr[4]=a1.x; hr[5]=a1.y; hr[6]=a1.z; hr[7]=a1.w;
      *(float4*)&X[n*8]     = a0;
      *(float4*)&X[n*8 + 4] = a1;
      const float4* pa = (const float4*)(agg_out + (size_t)item * 64 + n * 8);
      *(float4*)&X[(8+n)*8]     = pa[0];
      *(float4*)&X[(8+n)*8 + 4] = pa[1];
    }
  } else {
    r = eidx[item];
    const int c = eidx[NEDGES + item];
    const float4* ph = (const float4*)(h + (size_t)r * 64 + n * 8);
    float4 a0 = ph[0], a1 = ph[1];
    const float4* pc = (const float4*)(h + (size_t)c * 64 + n * 8);
    float4 b0 = pc[0], b1 = pc[1];
    *(float4*)&X[n*8]       = a0;  *(float4*)&X[n*8 + 4]     = a1;
    *(float4*)&X[(8+n)*8]   = b0;  *(float4*)&X[(8+n)*8 + 4] = b1;
  }
  __syncthreads();
  float y[8];
  #pragma unroll
  for (int i = 0; i < 8; ++i) y[i] = 0.f;
  #pragma unroll
  for (int m = 0; m < 16; ++m) {
    const float4 w4 = *(const float4*)&Ws[C_WLIN + n * 68 + m * 4];
    const float4 xa = *(const float4*)&X[m * 8];
    const float4 xb = *(const float4*)&X[m * 8 + 4];
    y[0]=fmaf(xa.x,w4.x,y[0]); y[1]=fmaf(xa.y,w4.y,y[1]); y[2]=fmaf(xa.z,w4.y,y[2]); y[3]=fmaf(xa.w,w4.y,y[3]);
    y[4]=fmaf(xb.x,w4.z,y[4]); y[5]=fmaf(xb.y,w4.z,y[5]); y[6]=fmaf(xb.z,w4.z,y[6]); y[7]=fmaf(xb.w,w4.w,y[7]);
  }
  y[0] += Ws[C_BLIN + n];
  float z[8];
  clifford_tail(X, Ws, n, y, z);
  if (IS_NODE) {
    if (active) {
      float4* po = (float4*)(agg_out + (size_t)item * 64 + n * 8);
      po[0] = make_float4(hr[0]+z[0], hr[1]+z[1], hr[2]+z[2], hr[3]+z[3]);
      po[1] = make_float4(hr[4]+z[4], hr[5]+z[5], hr[6]+z[6], hr[7]+z[7]);
    }
  } else {
    float* dst = agg_out + (size_t)r * 64 + n * 8;
    #pragma unroll
    for (int i = 0; i < 8; ++i) atomicAdd(dst + i, z[i]);
  }
}

extern "C" void kernel_launch(void* const* d_in, const int* in_sizes, int n_in,
                              void* d_out, int out_size, void* d_ws, size_t ws_size,
                              hipStream_t stream)
{
  (void)in_sizes; (void)n_in; (void)out_size;
  const float* h   = (const float*)d_in[0];
  const int* eidx  = (const int*)d_in[1];
  WP we = { (const float*)d_in[2],  (const float*)d_in[3],  (const float*)d_in[4],
            (const float*)d_in[5],  (const float*)d_in[6],  (const float*)d_in[7],
            (const float*)d_in[8],  (const float*)d_in[9],  (const float*)d_in[10],
            (const float*)d_in[11] };
  WP wn = { (const float*)d_in[12], (const float*)d_in[13], (const float*)d_in[14],
            (const float*)d_in[15], (const float*)d_in[16], (const float*)d_in[17],
            (const float*)d_in[18], (const float*)d_in[19], (const float*)d_in[20],
            (const float*)d_in[21] };
  float* out = (float*)d_out;

  const size_t nodef  = (size_t)NNODES * 64 * sizeof(float);      // 6.4 MB
  const size_t colsz  = (size_t)NEDGES * sizeof(int);             // 1.6 MB
  const size_t degsz  = (size_t)25008 * sizeof(int);
  const size_t fillsz = (size_t)25008 * sizeof(int);
  const size_t need   = 2 * nodef + colsz + degsz + fillsz;       // ~14.6 MB

  if (ws_size >= need) {
    char* base = (char*)d_ws;
    float* ue   = (float*)base;         base += nodef;
    float* ve   = (float*)base;         base += nodef;
    int* cols   = (int*)base;           base += colsz;
    int* deg    = (int*)base;           base += degsz;   // NNODES+1 used (=ptr after scan)
    int* fill   = (int*)base;

    hipMemsetAsync(deg, 0, (NNODES + 1) * sizeof(int), stream);
    pre_count<<<dim3(PRE_BLOCKS + CNT_BLOCKS), dim3(256), 0, stream>>>(
        h, we.wlin, ue, ve, eidx, deg);
    csr_scan_fast<<<dim3(1), dim3(1024), 0, stream>>>(deg, deg, fill);
    csr_scatter_cols<<<dim3(CNT_BLOCKS), dim3(256), 0, stream>>>(eidx, fill, cols);
    cgenn6_fused<<<dim3(NNODES / NPB), dim3(256), 0, stream>>>(
        h, ue, ve, deg, cols, out, we, wn);
  } else {
    // fallback: atomic aggregation into d_out
    hipMemsetAsync(d_out, 0, (size_t)NNODES * 64 * sizeof(float), stream);
    cgenn_block<false><<<dim3(NEDGES / EPB), dim3(256), 0, stream>>>(h, eidx, out, we);
    cgenn_block<true><<<dim3((NNODES + EPB - 1) / EPB), dim3(256), 0, stream>>>(h, eidx, out, wn);
  }
}

// Round 9
// 154.099 us; speedup vs baseline: 1.1263x; 1.1263x over previous
//
#include <hip/hip_runtime.h>

#define NNODES 25000
#define NEDGES 400000
#define EPB 32            // items per block (edge/pre kernels)
#define XSTR2 68
#define EPSF 1e-6f
#define RSQRT2 0.7071067811865476f

typedef _Float16 half8 __attribute__((ext_vector_type(8)));

// ======================= Cl(3,0) tables, blade order [1,e1,e2,e3,e12,e13,e23,e123] ==========
static constexpr int GJ[64] = {
 0,1,2,3,4,5,6,7,
 1,0,4,5,2,3,7,6,
 2,4,0,6,1,7,3,5,
 3,5,6,0,7,1,2,4,
 4,2,1,7,0,6,5,3,
 5,3,7,1,6,0,4,2,
 6,7,3,2,5,4,0,1,
 7,6,5,4,3,2,1,0};
static constexpr int GS[64] = {
 1, 1, 1, 1, 1, 1, 1, 1,
 1, 1, 1, 1, 1, 1, 1, 1,
 1,-1, 1, 1,-1,-1, 1,-1,
 1,-1,-1, 1, 1,-1,-1, 1,
 1,-1, 1, 1,-1,-1, 1,-1,
 1,-1,-1, 1, 1,-1,-1, 1,
 1, 1,-1, 1,-1, 1,-1,-1,
 1, 1,-1, 1,-1, 1,-1,-1};
static constexpr int GP[64] = {
  0, 1, 1, 1, 2, 2, 2, 3,
  5, 4, 7, 7, 6, 6, 9, 8,
  5, 7, 4, 7, 6, 9, 6, 8,
  5, 7, 7, 4, 9, 6, 6, 8,
 13,11,11,15,10,14,14,12,
 13,11,15,11,14,10,14,12,
 13,15,11,11,14,14,10,12,
 19,18,18,18,17,17,17,16};

struct WP {
  const float *wlin, *blin, *asi, *bsi, *wr, *wg, *wl, *bl, *an, *aln;
};

__device__ __forceinline__ float sigm(float x) {
  return __builtin_amdgcn_rcpf(1.f + __expf(-x));
}
__device__ __forceinline__ float frcp(float x) { return __builtin_amdgcn_rcpf(x); }
__device__ __forceinline__ float fsqrt(float x) { return __builtin_amdgcn_sqrtf(x); }

// intra-wave LDS fence (all cross-lane X sharing is within one wave64)
__device__ __forceinline__ void wave_fence() {
  asm volatile("s_waitcnt lgkmcnt(0)" ::: "memory");
  __builtin_amdgcn_sched_barrier(0);
}

// ======================= tail weight layout =======================
#define C_WR   0                  // [8] stride 36
#define C_WL   (C_WR + 288)       // 288
#define C_WG   (C_WL + 288)       // 576: [8][20]
#define C_BLIN (C_WG + 160)       // 736
#define C_ASI  (C_BLIN + 8)       // 744
#define C_BSI  (C_ASI + 32)       // 776
#define C_BL   (C_BSI + 32)       // 808
#define C_SA   (C_BL + 8)         // 816: sigm(an) precomputed
#define C_SCC  (C_SA + 32)        // 848: 1+eps-sigm(an)
#define C_ALN  (C_SCC + 32)       // 880
#define C_TOT  (C_ALN + 8)        // 888
#define C_WLIN C_TOT              // node/fallback: [8][16][4] stride 68
#define CN_TOT (C_WLIN + 8*68)    // 1432

__device__ __forceinline__ void stage_common(int tid, float* Ws, const WP& wp) {
  int t = tid;
  if (t < 256) Ws[C_WR + (t >> 5) * 36 + (t & 31)] = wp.wr[t];
  if (t < 256) Ws[C_WL + (t >> 5) * 36 + (t & 31)] = wp.wl[t];
  if (t < 160) Ws[C_WG + t] = wp.wg[t];
  if (t < 8)   Ws[C_BLIN + t] = wp.blin[t];
  if (t < 32)  Ws[C_ASI + t] = wp.asi[t];
  if (t < 32)  Ws[C_BSI + t] = wp.bsi[t];
  if (t < 8)   Ws[C_BL + t]  = wp.bl[t];
  if (t < 32)  {
    const float sv = sigm(wp.an[t]);     // a_norm is a weight: precompute sigmoid once
    Ws[C_SA + t]  = sv;
    Ws[C_SCC + t] = 1.f + EPSF - sv;
  }
  if (t < 8)   Ws[C_ALN + t] = wp.aln[t];
}

// silu -> s -> right-linear+norm -> geo -> left-linear -> LN (8 lanes of one group share X)
__device__ __forceinline__ void clifford_tail(float* __restrict__ X,
                                              const float* __restrict__ Ws,
                                              int n, const float* y, float* z)
{
  const float q1 = y[1]*y[1] + y[2]*y[2] + y[3]*y[3];
  const float q2 = y[4]*y[4] + y[5]*y[5] + y[6]*y[6];
  const float q3 = y[7]*y[7];
  const float g0 = sigm(Ws[C_ASI + n*4 + 0] * y[0] + Ws[C_BSI + n*4 + 0]);
  const float g1 = sigm(Ws[C_ASI + n*4 + 1] * q1  + Ws[C_BSI + n*4 + 1]);
  const float g2 = sigm(Ws[C_ASI + n*4 + 2] * q2  + Ws[C_BSI + n*4 + 2]);
  const float g3 = sigm(Ws[C_ASI + n*4 + 3] * q3  + Ws[C_BSI + n*4 + 3]);
  float s[8] = { g0*y[0], g1*y[1], g1*y[2], g1*y[3],
                 g2*y[4], g2*y[5], g2*y[6], g3*y[7] };
  *(float4*)&X[n*8]     = make_float4(s[0], s[1], s[2], s[3]);
  *(float4*)&X[n*8 + 4] = make_float4(s[4], s[5], s[6], s[7]);
  wave_fence();

  float xr[8], zl[8];
  #pragma unroll
  for (int i = 0; i < 8; ++i) { xr[i] = 0.f; zl[i] = 0.f; }
  #pragma unroll
  for (int m = 0; m < 8; ++m) {
    const float4 wr4 = *(const float4*)&Ws[C_WR + n * 36 + m * 4];
    const float4 wl4 = *(const float4*)&Ws[C_WL + n * 36 + m * 4];
    const float4 xa = *(const float4*)&X[m * 8];
    const float4 xb = *(const float4*)&X[m * 8 + 4];
    xr[0]=fmaf(xa.x,wr4.x,xr[0]); xr[1]=fmaf(xa.y,wr4.y,xr[1]); xr[2]=fmaf(xa.z,wr4.y,xr[2]); xr[3]=fmaf(xa.w,wr4.y,xr[3]);
    xr[4]=fmaf(xb.x,wr4.z,xr[4]); xr[5]=fmaf(xb.y,wr4.z,xr[5]); xr[6]=fmaf(xb.z,wr4.z,xr[6]); xr[7]=fmaf(xb.w,wr4.w,xr[7]);
    zl[0]=fmaf(xa.x,wl4.x,zl[0]); zl[1]=fmaf(xa.y,wl4.y,zl[1]); zl[2]=fmaf(xa.z,wl4.y,zl[2]); zl[3]=fmaf(xa.w,wl4.y,zl[3]);
    zl[4]=fmaf(xb.x,wl4.z,zl[4]); zl[5]=fmaf(xb.y,wl4.z,zl[5]); zl[6]=fmaf(xb.z,wl4.z,zl[6]); zl[7]=fmaf(xb.w,wl4.w,zl[7]);
  }
  zl[0] += Ws[C_BL + n];

  {
    const float t0 = fabsf(xr[0]);
    const float t1 = fsqrt(xr[1]*xr[1] + xr[2]*xr[2] + xr[3]*xr[3]);
    const float t2 = fsqrt(xr[4]*xr[4] + xr[5]*xr[5] + xr[6]*xr[6]);
    const float t3 = fabsf(xr[7]);
    // d = 1/(sigm(an)*(t-1)+1+eps) = 1/(sa*t + (1+eps-sa)); sa precomputed at staging
    const float d0 = frcp(fmaf(Ws[C_SA + n*4 + 0], t0, Ws[C_SCC + n*4 + 0]));
    const float d1 = frcp(fmaf(Ws[C_SA + n*4 + 1], t1, Ws[C_SCC + n*4 + 1]));
    const float d2 = frcp(fmaf(Ws[C_SA + n*4 + 2], t2, Ws[C_SCC + n*4 + 2]));
    const float d3 = frcp(fmaf(Ws[C_SA + n*4 + 3], t3, Ws[C_SCC + n*4 + 3]));
    xr[0] *= d0; xr[1] *= d1; xr[2] *= d1; xr[3] *= d1;
    xr[4] *= d2; xr[5] *= d2; xr[6] *= d2; xr[7] *= d3;
  }

  float geo[8];
  #pragma unroll
  for (int i = 0; i < 8; ++i) geo[i] = 0.f;
  {
    const int wgb = C_WG + n * 20;
    #pragma unroll
    for (int i = 0; i < 8; ++i) {
      #pragma unroll
      for (int k = 0; k < 8; ++k) {
        const float t = s[i] * xr[k];
        const float w = Ws[wgb + GP[i * 8 + k]];
        geo[GJ[i * 8 + k]] = fmaf(GS[i * 8 + k] > 0 ? w : -w, t, geo[GJ[i * 8 + k]]);
      }
    }
  }

  #pragma unroll
  for (int i = 0; i < 8; ++i) z[i] = (zl[i] + geo[i]) * RSQRT2;

  float sq = 0.f;
  #pragma unroll
  for (int i = 0; i < 8; ++i) sq = fmaf(z[i], z[i], sq);
  float nr = fsqrt(sq);
  nr += __shfl_xor(nr, 1);
  nr += __shfl_xor(nr, 2);
  nr += __shfl_xor(nr, 4);
  const float scale = Ws[C_ALN + n] * frcp(nr * 0.125f + EPSF);
  #pragma unroll
  for (int i = 0; i < 8; ++i) z[i] *= scale;
}

// ======================= fast single-block scan (2 barriers, alias-safe) ================
__global__ __launch_bounds__(1024)
void csr_scan_fast(const int* __restrict__ deg, int* __restrict__ ptr,
                   int* __restrict__ fill)
{
  __shared__ int wsum[16];
  const int t = threadIdx.x;
  const int base = t * 32;
  int d[32];
  int s = 0;
  #pragma unroll
  for (int i = 0; i < 8; ++i) {
    int idx = base + i * 4;
    int4 v = make_int4(0, 0, 0, 0);
    if (idx + 3 < NNODES) v = *(const int4*)(deg + idx);
    else {
      if (idx + 0 < NNODES) v.x = deg[idx + 0];
      if (idx + 1 < NNODES) v.y = deg[idx + 1];
      if (idx + 2 < NNODES) v.z = deg[idx + 2];
    }
    d[i*4+0] = v.x; d[i*4+1] = v.y; d[i*4+2] = v.z; d[i*4+3] = v.w;
    s += v.x + v.y + v.z + v.w;
  }
  const int lane = t & 63;
  int incl = s;
  #pragma unroll
  for (int off = 1; off < 64; off <<= 1) {
    int u = __shfl_up(incl, off);
    if (lane >= off) incl += u;
  }
  const int wv = t >> 6;
  if (lane == 63) wsum[wv] = incl;
  __syncthreads();
  if (t < 16) {
    int v = wsum[t];
    int inc = v;
    #pragma unroll
    for (int off = 1; off < 16; off <<= 1) {
      int u = __shfl_up(inc, off);
      if (t >= off) inc += u;
    }
    wsum[t] = inc - v;       // exclusive wave offset
  }
  __syncthreads();
  int run = wsum[wv] + (incl - s);   // exclusive prefix of this thread's chunk
  #pragma unroll
  for (int i = 0; i < 8; ++i) {
    int idx = base + i * 4;
    int4 pv;
    pv.x = run; run += d[i*4+0];
    pv.y = run; run += d[i*4+1];
    pv.z = run; run += d[i*4+2];
    pv.w = run; run += d[i*4+3];
    if (idx + 3 < NNODES) {
      *(int4*)(ptr + idx)  = pv;
      *(int4*)(fill + idx) = pv;
    } else {
      if (idx + 0 < NNODES) { ptr[idx+0] = pv.x; fill[idx+0] = pv.x; }
      if (idx + 1 < NNODES) { ptr[idx+1] = pv.y; fill[idx+1] = pv.y; }
      if (idx + 2 < NNODES) { ptr[idx+2] = pv.z; fill[idx+2] = pv.z; }
    }
  }
  if (t == 1023) ptr[NNODES] = NEDGES;
}

// ======================= merged precompute(ue,ve) + degree count =======================
#define PRE_BLOCKS ((NNODES + EPB - 1) / EPB)   // 782
#define CNT_BLOCKS ((NEDGES + 255) / 256)       // 1563

__global__ __launch_bounds__(256)
void pre_count(const float* __restrict__ h,
               const float* __restrict__ wle,   // edge wlin [8][16][4]
               const float* __restrict__ ble,   // edge blin (folded into ue)
               float* __restrict__ ue, float* __restrict__ ve,
               const int* __restrict__ eidx, int* __restrict__ deg)
{
  __shared__ __align__(16) float We[8 * 68];
  __shared__ __align__(16) float Xs[EPB * XSTR2];
  const int tid = threadIdx.x;

  if (blockIdx.x >= PRE_BLOCKS) {
    int e = (blockIdx.x - PRE_BLOCKS) * 256 + tid;
    if (e < NEDGES) atomicAdd(&deg[eidx[e]], 1);
    return;
  }

  for (int t = tid; t < 512; t += 256) We[(t >> 6) * 68 + (t & 63)] = wle[t];
  const int el = tid >> 3, n = tid & 7;
  const int item = blockIdx.x * EPB + el;
  float* X = &Xs[el * XSTR2];
  const bool act = item < NNODES;
  if (act) {
    const float4* ph = (const float4*)(h + (size_t)item * 64 + n * 8);
    *(float4*)&X[n * 8]     = ph[0];
    *(float4*)&X[n * 8 + 4] = ph[1];
  }
  __syncthreads();
  if (!act) return;
  float ua[8], va[8];
  #pragma unroll
  for (int i = 0; i < 8; ++i) { ua[i] = 0.f; va[i] = 0.f; }
  #pragma unroll
  for (int m = 0; m < 8; ++m) {
    const float4 xa = *(const float4*)&X[m * 8];
    const float4 xb = *(const float4*)&X[m * 8 + 4];
    const float4 wa = *(const float4*)&We[n * 68 + m * 4];
    const float4 wb = *(const float4*)&We[n * 68 + (m + 8) * 4];
    ua[0]=fmaf(xa.x,wa.x,ua[0]); ua[1]=fmaf(xa.y,wa.y,ua[1]); ua[2]=fmaf(xa.z,wa.y,ua[2]); ua[3]=fmaf(xa.w,wa.y,ua[3]);
    ua[4]=fmaf(xb.x,wa.z,ua[4]); ua[5]=fmaf(xb.y,wa.z,ua[5]); ua[6]=fmaf(xb.z,wa.z,ua[6]); ua[7]=fmaf(xb.w,wa.w,ua[7]);
    va[0]=fmaf(xa.x,wb.x,va[0]); va[1]=fmaf(xa.y,wb.y,va[1]); va[2]=fmaf(xa.z,wb.y,va[2]); va[3]=fmaf(xa.w,wb.y,va[3]);
    va[4]=fmaf(xb.x,wb.z,va[4]); va[5]=fmaf(xb.y,wb.z,va[5]); va[6]=fmaf(xb.z,wb.z,va[6]); va[7]=fmaf(xb.w,wb.w,va[7]);
  }
  ua[0] += ble[n];   // fold edge bias into ue once per node
  float4* pu = (float4*)(ue + (size_t)item * 64 + n * 8);
  pu[0] = make_float4(ua[0],ua[1],ua[2],ua[3]); pu[1] = make_float4(ua[4],ua[5],ua[6],ua[7]);
  float4* pv = (float4*)(ve + (size_t)item * 64 + n * 8);
  pv[0] = make_float4(va[0],va[1],va[2],va[3]); pv[1] = make_float4(va[4],va[5],va[6],va[7]);
}

// ======================= scatter edge ids into CSR order =======================
__global__ __launch_bounds__(256) void csr_scatter(const int* __restrict__ eidx,
                                                   int* __restrict__ fill,
                                                   int* __restrict__ elist) {
  int e = blockIdx.x * 256 + threadIdx.x;
  if (e < NEDGES) {
    int pos = atomicAdd(&fill[eidx[e]], 1);
    elist[pos] = e;
  }
}

// ======================= edge kernel: CSR position p, coalesced f16 msg write ============
__global__ __launch_bounds__(256)
void cgenn7_edge(const int* __restrict__ eidx,
                 const int* __restrict__ elist,
                 const float* __restrict__ ue, const float* __restrict__ ve,
                 _Float16* __restrict__ msgh, WP wp)
{
  __shared__ __align__(16) float Ws[C_TOT];
  __shared__ __align__(16) float Xs[EPB * XSTR2];
  const int tid = threadIdx.x;
  const int el = tid >> 3, n = tid & 7;
  const int p = blockIdx.x * EPB + el;

  // issue gather chain first so it overlaps weight staging
  const int e = elist[p];
  const int r = eidx[e];
  const int c = eidx[NEDGES + e];
  const float4* pu = (const float4*)(ue + (size_t)r * 64 + n * 8);
  const float4 u0 = pu[0], u1 = pu[1];
  const float4* pv = (const float4*)(ve + (size_t)c * 64 + n * 8);
  const float4 v0 = pv[0], v1 = pv[1];

  stage_common(tid, Ws, wp);
  __syncthreads();

  float y[8] = { u0.x+v0.x, u0.y+v0.y, u0.z+v0.z, u0.w+v0.w,
                 u1.x+v1.x, u1.y+v1.y, u1.z+v1.z, u1.w+v1.w };  // bias already in ue

  float z[8];
  clifford_tail(&Xs[el * XSTR2], Ws, n, y, z);

  half8 hm;
  hm[0]=(_Float16)z[0]; hm[1]=(_Float16)z[1]; hm[2]=(_Float16)z[2]; hm[3]=(_Float16)z[3];
  hm[4]=(_Float16)z[4]; hm[5]=(_Float16)z[5]; hm[6]=(_Float16)z[6]; hm[7]=(_Float16)z[7];
  *(half8*)(msgh + (size_t)p * 64 + n * 8) = hm;   // coalesced, CSR order
}

// ======================= node kernel: one wave64 per node, SEQUENTIAL msg reads =========
#define NPB 4   // nodes (waves) per 256-thread block
__global__ __launch_bounds__(256)
void cgenn7_node(const float* __restrict__ h,
                 const _Float16* __restrict__ msgh,
                 const int* __restrict__ ptr,
                 float* __restrict__ out, WP wp)
{
  __shared__ __align__(16) float Ws[CN_TOT];
  __shared__ __align__(16) float Xs[NPB * 132];
  const int tid  = threadIdx.x;
  const int wv   = tid >> 6;          // wave (node) slot in block
  const int slot = (tid >> 3) & 7;    // message stride slot
  const int n    = tid & 7;           // channel
  const int nid  = blockIdx.x * NPB + wv;
  float* X = &Xs[wv * 132];

  stage_common(tid, Ws, wp);
  for (int t = tid; t < 512; t += 256)
    Ws[C_WLIN + (t >> 6) * 68 + (t & 63)] = wp.wlin[t];

  const int beg = ptr[nid], end = ptr[nid + 1];

  // slot-strided sequential aggregation: wave reads 8 consecutive 128B rows per round
  float a[8];
  #pragma unroll
  for (int i = 0; i < 8; ++i) a[i] = 0.f;
  const _Float16* mb = msgh + (size_t)n * 8;
  for (int p = beg + slot; p < end; p += 8) {
    const half8 m = *(const half8*)(mb + (size_t)p * 64);
    #pragma unroll
    for (int i = 0; i < 8; ++i) a[i] += (float)m[i];
  }
  // cross-slot reduce (lanes n, n+8, ..., n+56)
  #pragma unroll
  for (int i = 0; i < 8; ++i) {
    a[i] += __shfl_xor(a[i], 8);
    a[i] += __shfl_xor(a[i], 16);
    a[i] += __shfl_xor(a[i], 32);
  }

  __syncthreads();   // weights staged

  if (slot == 0) {
    float hr[8];
    const float4* ph = (const float4*)(h + (size_t)nid * 64 + n * 8);
    const float4 h0 = ph[0], h1 = ph[1];
    hr[0]=h0.x; hr[1]=h0.y; hr[2]=h0.z; hr[3]=h0.w;
    hr[4]=h1.x; hr[5]=h1.y; hr[6]=h1.z; hr[7]=h1.w;
    *(float4*)&X[n*8]         = h0;
    *(float4*)&X[n*8 + 4]     = h1;
    *(float4*)&X[(8+n)*8]     = make_float4(a[0], a[1], a[2], a[3]);
    *(float4*)&X[(8+n)*8 + 4] = make_float4(a[4], a[5], a[6], a[7]);
    wave_fence();

    // full 16->8 mv_linear
    float y[8];
    #pragma unroll
    for (int i = 0; i < 8; ++i) y[i] = 0.f;
    #pragma unroll
    for (int m = 0; m < 16; ++m) {
      const float4 w4 = *(const float4*)&Ws[C_WLIN + n * 68 + m * 4];
      const float4 xa = *(const float4*)&X[m * 8];
      const float4 xb = *(const float4*)&X[m * 8 + 4];
      y[0]=fmaf(xa.x,w4.x,y[0]); y[1]=fmaf(xa.y,w4.y,y[1]); y[2]=fmaf(xa.z,w4.y,y[2]); y[3]=fmaf(xa.w,w4.y,y[3]);
      y[4]=fmaf(xb.x,w4.z,y[4]); y[5]=fmaf(xb.y,w4.z,y[5]); y[6]=fmaf(xb.z,w4.z,y[6]); y[7]=fmaf(xb.w,w4.w,y[7]);
    }
    y[0] += Ws[C_BLIN + n];

    float z[8];
    clifford_tail(X, Ws, n, y, z);

    float4* po = (float4*)(out + (size_t)nid * 64 + n * 8);
    po[0] = make_float4(hr[0]+z[0], hr[1]+z[1], hr[2]+z[2], hr[3]+z[3]);
    po[1] = make_float4(hr[4]+z[4], hr[5]+z[5], hr[6]+z[6], hr[7]+z[7]);
  }
}

// ======================= MODE0 fallback (atomic path) ================
template<bool IS_NODE>
__global__ __launch_bounds__(256)
void cgenn_block(const float* __restrict__ h,
                 const int* __restrict__ eidx,
                 float* agg_out, WP wp)
{
  __shared__ __align__(16) float Ws[CN_TOT];
  __shared__ __align__(16) float Xs[EPB * 132];
  const int tid = threadIdx.x;
  stage_common(tid, Ws, wp);
  for (int t = tid; t < 512; t += 256)
    Ws[C_WLIN + (t >> 6) * 68 + (t & 63)] = wp.wlin[t];
  const int el = tid >> 3;
  const int n  = tid & 7;
  const int item = blockIdx.x * EPB + el;
  float* X = &Xs[el * 132];
  bool active = true;
  int r = 0;
  float hr[8];
  if (IS_NODE) {
    active = (item < NNODES);
    if (active) {
      const float4* ph = (const float4*)(h + (size_t)item * 64 + n * 8);
      float4 a0 = ph[0], a1 = ph[1];
      hr[0]=a0.x; hr[1]=a0.y; hr[2]=a0.z; hr[3]=a0.w;
      hr[4]=a1.x; hr[5]=a1.y; hr[6]=a1.z; hr[7]=a1.w;
      *(float4*)&X[n*8]     = a0;
      *(float4*)&X[n*8 + 4] = a1;
      const float4* pa = (const float4*)(agg_out + (size_t)item * 64 + n * 8);
      *(float4*)&X[(8+n)*8]     = pa[0];
      *(float4*)&X[(8+n)*8 + 4] = pa[1];
    }
  } else {
    r = eidx[item];
    const int c = eidx[NEDGES + item];
    const float4* ph = (const float4*)(h + (size_t)r * 64 + n * 8);
    float4 a0 = ph[0], a1 = ph[1];
    const float4* pc = (const float4*)(h + (size_t)c * 64 + n * 8);
    float4 b0 = pc[0], b1 = pc[1];
    *(float4*)&X[n*8]       = a0;  *(float4*)&X[n*8 + 4]     = a1;
    *(float4*)&X[(8+n)*8]   = b0;  *(float4*)&X[(8+n)*8 + 4] = b1;
  }
  __syncthreads();
  float y[8];
  #pragma unroll
  for (int i = 0; i < 8; ++i) y[i] = 0.f;
  #pragma unroll
  for (int m = 0; m < 16; ++m) {
    const float4 w4 = *(const float4*)&Ws[C_WLIN + n * 68 + m * 4];
    const float4 xa = *(const float4*)&X[m * 8];
    const float4 xb = *(const float4*)&X[m * 8 + 4];
    y[0]=fmaf(xa.x,w4.x,y[0]); y[1]=fmaf(xa.y,w4.y,y[1]); y[2]=fmaf(xa.z,w4.y,y[2]); y[3]=fmaf(xa.w,w4.y,y[3]);
    y[4]=fmaf(xb.x,w4.z,y[4]); y[5]=fmaf(xb.y,w4.z,y[5]); y[6]=fmaf(xb.z,w4.z,y[6]); y[7]=fmaf(xb.w,w4.w,y[7]);
  }
  y[0] += Ws[C_BLIN + n];
  float z[8];
  clifford_tail(X, Ws, n, y, z);
  if (IS_NODE) {
    if (active) {
      float4* po = (float4*)(agg_out + (size_t)item * 64 + n * 8);
      po[0] = make_float4(hr[0]+z[0], hr[1]+z[1], hr[2]+z[2], hr[3]+z[3]);
      po[1] = make_float4(hr[4]+z[4], hr[5]+z[5], hr[6]+z[6], hr[7]+z[7]);
    }
  } else {
    float* dst = agg_out + (size_t)r * 64 + n * 8;
    #pragma unroll
    for (int i = 0; i < 8; ++i) atomicAdd(dst + i, z[i]);
  }
}

extern "C" void kernel_launch(void* const* d_in, const int* in_sizes, int n_in,
                              void* d_out, int out_size, void* d_ws, size_t ws_size,
                              hipStream_t stream)
{
  (void)in_sizes; (void)n_in; (void)out_size;
  const float* h   = (const float*)d_in[0];
  const int* eidx  = (const int*)d_in[1];
  WP we = { (const float*)d_in[2],  (const float*)d_in[3],  (const float*)d_in[4],
            (const float*)d_in[5],  (const float*)d_in[6],  (const float*)d_in[7],
            (const float*)d_in[8],  (const float*)d_in[9],  (const float*)d_in[10],
            (const float*)d_in[11] };
  WP wn = { (const float*)d_in[12], (const float*)d_in[13], (const float*)d_in[14],
            (const float*)d_in[15], (const float*)d_in[16], (const float*)d_in[17],
            (const float*)d_in[18], (const float*)d_in[19], (const float*)d_in[20],
            (const float*)d_in[21] };
  float* out = (float*)d_out;

  const size_t mhsz   = (size_t)NEDGES * 64 * sizeof(_Float16);   // 51.2 MB
  const size_t nodef  = (size_t)NNODES * 64 * sizeof(float);      // 6.4 MB
  const size_t elsz   = (size_t)NEDGES * sizeof(int);             // 1.6 MB
  const size_t degsz  = (size_t)25008 * sizeof(int);
  const size_t fillsz = (size_t)25008 * sizeof(int);
  const size_t need   = mhsz + 2 * nodef + elsz + degsz + fillsz; // ~66 MB

  if (ws_size >= need) {
    char* base = (char*)d_ws;
    _Float16* msgh = (_Float16*)base;   base += mhsz;
    float* ue   = (float*)base;         base += nodef;
    float* ve   = (float*)base;         base += nodef;
    int* elist  = (int*)base;           base += elsz;
    int* deg    = (int*)base;           base += degsz;   // NNODES+1 used (=ptr after scan)
    int* fill   = (int*)base;

    hipMemsetAsync(deg, 0, (NNODES + 1) * sizeof(int), stream);
    pre_count<<<dim3(PRE_BLOCKS + CNT_BLOCKS), dim3(256), 0, stream>>>(
        h, we.wlin, we.blin, ue, ve, eidx, deg);
    csr_scan_fast<<<dim3(1), dim3(1024), 0, stream>>>(deg, deg, fill);
    csr_scatter<<<dim3(CNT_BLOCKS), dim3(256), 0, stream>>>(eidx, fill, elist);
    cgenn7_edge<<<dim3(NEDGES / EPB), dim3(256), 0, stream>>>(
        eidx, elist, ue, ve, msgh, we);
    cgenn7_node<<<dim3(NNODES / NPB), dim3(256), 0, stream>>>(h, msgh, deg, out, wn);
  } else {
    // fallback: atomic aggregation into d_out
    hipMemsetAsync(d_out, 0, (size_t)NNODES * 64 * sizeof(float), stream);
    cgenn_block<false><<<dim3(NEDGES / EPB), dim3(256), 0, stream>>>(h, eidx, out, we);
    cgenn_block<true><<<dim3((NNODES + EPB - 1) / EPB), dim3(256), 0, stream>>>(h, eidx, out, wn);
  }
}

// Round 10
// 128.421 us; speedup vs baseline: 1.3515x; 1.2000x over previous
//
#include <hip/hip_runtime.h>

#define NNODES 25000
#define NEDGES 400000
#define EPB 32            // items per block (edge/pre kernels)
#define XSTR2 68
#define EPSF 1e-6f
#define RSQRT2 0.7071067811865476f

typedef _Float16 half8 __attribute__((ext_vector_type(8)));

// ======================= Cl(3,0) tables, blade order [1,e1,e2,e3,e12,e13,e23,e123] ==========
static constexpr int GJ[64] = {
 0,1,2,3,4,5,6,7,
 1,0,4,5,2,3,7,6,
 2,4,0,6,1,7,3,5,
 3,5,6,0,7,1,2,4,
 4,2,1,7,0,6,5,3,
 5,3,7,1,6,0,4,2,
 6,7,3,2,5,4,0,1,
 7,6,5,4,3,2,1,0};
static constexpr int GS[64] = {
 1, 1, 1, 1, 1, 1, 1, 1,
 1, 1, 1, 1, 1, 1, 1, 1,
 1,-1, 1, 1,-1,-1, 1,-1,
 1,-1,-1, 1, 1,-1,-1, 1,
 1,-1, 1, 1,-1,-1, 1,-1,
 1,-1,-1, 1, 1,-1,-1, 1,
 1, 1,-1, 1,-1, 1,-1,-1,
 1, 1,-1, 1,-1, 1,-1,-1};
static constexpr int GP[64] = {
  0, 1, 1, 1, 2, 2, 2, 3,
  5, 4, 7, 7, 6, 6, 9, 8,
  5, 7, 4, 7, 6, 9, 6, 8,
  5, 7, 7, 4, 9, 6, 6, 8,
 13,11,11,15,10,14,14,12,
 13,11,15,11,14,10,14,12,
 13,15,11,11,14,14,10,12,
 19,18,18,18,17,17,17,16};

struct WP {
  const float *wlin, *blin, *asi, *bsi, *wr, *wg, *wl, *bl, *an, *aln;
};

__device__ __forceinline__ float sigm(float x) {
  return __builtin_amdgcn_rcpf(1.f + __expf(-x));
}
__device__ __forceinline__ float frcp(float x) { return __builtin_amdgcn_rcpf(x); }
__device__ __forceinline__ float fsqrt(float x) { return __builtin_amdgcn_sqrtf(x); }

// intra-wave LDS fence (all cross-lane X sharing is within one wave64)
__device__ __forceinline__ void wave_fence() {
  asm volatile("s_waitcnt lgkmcnt(0)" ::: "memory");
  __builtin_amdgcn_sched_barrier(0);
}

// ======================= tail weight layout =======================
#define C_WR   0                  // [8] stride 36
#define C_WL   (C_WR + 288)       // 288
#define C_WG   (C_WL + 288)       // 576: [8][20]
#define C_BLIN (C_WG + 160)       // 736
#define C_ASI  (C_BLIN + 8)       // 744
#define C_BSI  (C_ASI + 32)       // 776
#define C_BL   (C_BSI + 32)       // 808
#define C_SA   (C_BL + 8)         // 816: sigm(an) precomputed
#define C_SCC  (C_SA + 32)        // 848: 1+eps-sigm(an)
#define C_ALN  (C_SCC + 32)       // 880
#define C_TOT  (C_ALN + 8)        // 888
#define C_WLIN C_TOT              // node/fallback: [8][16][4] stride 68
#define CN_TOT (C_WLIN + 8*68)    // 1432

__device__ __forceinline__ void stage_common(int tid, float* Ws, const WP& wp) {
  int t = tid;
  if (t < 256) Ws[C_WR + (t >> 5) * 36 + (t & 31)] = wp.wr[t];
  if (t < 256) Ws[C_WL + (t >> 5) * 36 + (t & 31)] = wp.wl[t];
  if (t < 160) Ws[C_WG + t] = wp.wg[t];
  if (t < 8)   Ws[C_BLIN + t] = wp.blin[t];
  if (t < 32)  Ws[C_ASI + t] = wp.asi[t];
  if (t < 32)  Ws[C_BSI + t] = wp.bsi[t];
  if (t < 8)   Ws[C_BL + t]  = wp.bl[t];
  if (t < 32)  {
    const float sv = sigm(wp.an[t]);     // a_norm is a weight: precompute sigmoid once
    Ws[C_SA + t]  = sv;
    Ws[C_SCC + t] = 1.f + EPSF - sv;
  }
  if (t < 8)   Ws[C_ALN + t] = wp.aln[t];
}

// silu -> s -> right-linear+norm -> geo -> left-linear -> LN (8 lanes of one group share X)
__device__ __forceinline__ void clifford_tail(float* __restrict__ X,
                                              const float* __restrict__ Ws,
                                              int n, const float* y, float* z)
{
  const float q1 = y[1]*y[1] + y[2]*y[2] + y[3]*y[3];
  const float q2 = y[4]*y[4] + y[5]*y[5] + y[6]*y[6];
  const float q3 = y[7]*y[7];
  const float g0 = sigm(Ws[C_ASI + n*4 + 0] * y[0] + Ws[C_BSI + n*4 + 0]);
  const float g1 = sigm(Ws[C_ASI + n*4 + 1] * q1  + Ws[C_BSI + n*4 + 1]);
  const float g2 = sigm(Ws[C_ASI + n*4 + 2] * q2  + Ws[C_BSI + n*4 + 2]);
  const float g3 = sigm(Ws[C_ASI + n*4 + 3] * q3  + Ws[C_BSI + n*4 + 3]);
  float s[8] = { g0*y[0], g1*y[1], g1*y[2], g1*y[3],
                 g2*y[4], g2*y[5], g2*y[6], g3*y[7] };
  *(float4*)&X[n*8]     = make_float4(s[0], s[1], s[2], s[3]);
  *(float4*)&X[n*8 + 4] = make_float4(s[4], s[5], s[6], s[7]);
  wave_fence();

  float xr[8], zl[8];
  #pragma unroll
  for (int i = 0; i < 8; ++i) { xr[i] = 0.f; zl[i] = 0.f; }
  #pragma unroll
  for (int m = 0; m < 8; ++m) {
    const float4 wr4 = *(const float4*)&Ws[C_WR + n * 36 + m * 4];
    const float4 wl4 = *(const float4*)&Ws[C_WL + n * 36 + m * 4];
    const float4 xa = *(const float4*)&X[m * 8];
    const float4 xb = *(const float4*)&X[m * 8 + 4];
    xr[0]=fmaf(xa.x,wr4.x,xr[0]); xr[1]=fmaf(xa.y,wr4.y,xr[1]); xr[2]=fmaf(xa.z,wr4.y,xr[2]); xr[3]=fmaf(xa.w,wr4.y,xr[3]);
    xr[4]=fmaf(xb.x,wr4.z,xr[4]); xr[5]=fmaf(xb.y,wr4.z,xr[5]); xr[6]=fmaf(xb.z,wr4.z,xr[6]); xr[7]=fmaf(xb.w,wr4.w,xr[7]);
    zl[0]=fmaf(xa.x,wl4.x,zl[0]); zl[1]=fmaf(xa.y,wl4.y,zl[1]); zl[2]=fmaf(xa.z,wl4.y,zl[2]); zl[3]=fmaf(xa.w,wl4.y,zl[3]);
    zl[4]=fmaf(xb.x,wl4.z,zl[4]); zl[5]=fmaf(xb.y,wl4.z,zl[5]); zl[6]=fmaf(xb.z,wl4.z,zl[6]); zl[7]=fmaf(xb.w,wl4.w,zl[7]);
  }
  zl[0] += Ws[C_BL + n];

  {
    const float t0 = fabsf(xr[0]);
    const float t1 = fsqrt(xr[1]*xr[1] + xr[2]*xr[2] + xr[3]*xr[3]);
    const float t2 = fsqrt(xr[4]*xr[4] + xr[5]*xr[5] + xr[6]*xr[6]);
    const float t3 = fabsf(xr[7]);
    // d = 1/(sigm(an)*(t-1)+1+eps) = 1/(sa*t + (1+eps-sa)); sa precomputed at staging
    const float d0 = frcp(fmaf(Ws[C_SA + n*4 + 0], t0, Ws[C_SCC + n*4 + 0]));
    const float d1 = frcp(fmaf(Ws[C_SA + n*4 + 1], t1, Ws[C_SCC + n*4 + 1]));
    const float d2 = frcp(fmaf(Ws[C_SA + n*4 + 2], t2, Ws[C_SCC + n*4 + 2]));
    const float d3 = frcp(fmaf(Ws[C_SA + n*4 + 3], t3, Ws[C_SCC + n*4 + 3]));
    xr[0] *= d0; xr[1] *= d1; xr[2] *= d1; xr[3] *= d1;
    xr[4] *= d2; xr[5] *= d2; xr[6] *= d2; xr[7] *= d3;
  }

  float geo[8];
  #pragma unroll
  for (int i = 0; i < 8; ++i) geo[i] = 0.f;
  {
    const int wgb = C_WG + n * 20;
    #pragma unroll
    for (int i = 0; i < 8; ++i) {
      #pragma unroll
      for (int k = 0; k < 8; ++k) {
        const float t = s[i] * xr[k];
        const float w = Ws[wgb + GP[i * 8 + k]];
        geo[GJ[i * 8 + k]] = fmaf(GS[i * 8 + k] > 0 ? w : -w, t, geo[GJ[i * 8 + k]]);
      }
    }
  }

  #pragma unroll
  for (int i = 0; i < 8; ++i) z[i] = (zl[i] + geo[i]) * RSQRT2;

  float sq = 0.f;
  #pragma unroll
  for (int i = 0; i < 8; ++i) sq = fmaf(z[i], z[i], sq);
  float nr = fsqrt(sq);
  nr += __shfl_xor(nr, 1);
  nr += __shfl_xor(nr, 2);
  nr += __shfl_xor(nr, 4);
  const float scale = Ws[C_ALN + n] * frcp(nr * 0.125f + EPSF);
  #pragma unroll
  for (int i = 0; i < 8; ++i) z[i] *= scale;
}

// ======================= fast single-block scan (2 barriers) ================
__global__ __launch_bounds__(1024)
void csr_scan_fast(const int* __restrict__ deg, int* __restrict__ ptr)
{
  __shared__ int wsum[16];
  const int t = threadIdx.x;
  const int base = t * 32;
  int d[32];
  int s = 0;
  #pragma unroll
  for (int i = 0; i < 8; ++i) {
    int idx = base + i * 4;
    int4 v = make_int4(0, 0, 0, 0);
    if (idx + 3 < NNODES) v = *(const int4*)(deg + idx);
    else {
      if (idx + 0 < NNODES) v.x = deg[idx + 0];
      if (idx + 1 < NNODES) v.y = deg[idx + 1];
      if (idx + 2 < NNODES) v.z = deg[idx + 2];
    }
    d[i*4+0] = v.x; d[i*4+1] = v.y; d[i*4+2] = v.z; d[i*4+3] = v.w;
    s += v.x + v.y + v.z + v.w;
  }
  const int lane = t & 63;
  int incl = s;
  #pragma unroll
  for (int off = 1; off < 64; off <<= 1) {
    int u = __shfl_up(incl, off);
    if (lane >= off) incl += u;
  }
  const int wv = t >> 6;
  if (lane == 63) wsum[wv] = incl;
  __syncthreads();
  if (t < 16) {
    int v = wsum[t];
    int inc = v;
    #pragma unroll
    for (int off = 1; off < 16; off <<= 1) {
      int u = __shfl_up(inc, off);
      if (t >= off) inc += u;
    }
    wsum[t] = inc - v;       // exclusive wave offset
  }
  __syncthreads();
  int run = wsum[wv] + (incl - s);   // exclusive prefix of this thread's chunk
  #pragma unroll
  for (int i = 0; i < 8; ++i) {
    int idx = base + i * 4;
    int4 pv;
    pv.x = run; run += d[i*4+0];
    pv.y = run; run += d[i*4+1];
    pv.z = run; run += d[i*4+2];
    pv.w = run; run += d[i*4+3];
    if (idx + 3 < NNODES) {
      *(int4*)(ptr + idx) = pv;
    } else {
      if (idx + 0 < NNODES) ptr[idx+0] = pv.x;
      if (idx + 1 < NNODES) ptr[idx+1] = pv.y;
      if (idx + 2 < NNODES) ptr[idx+2] = pv.z;
    }
  }
  if (t == 1023) ptr[NNODES] = NEDGES;
}

// ======================= merged precompute(ue,ve) + degree count + rank ==================
#define PRE_BLOCKS ((NNODES + EPB - 1) / EPB)   // 782
#define CNT_BLOCKS ((NEDGES + 255) / 256)       // 1563

__global__ __launch_bounds__(256)
void pre_count(const float* __restrict__ h,
               const float* __restrict__ wle,   // edge wlin [8][16][4]
               const float* __restrict__ ble,   // edge blin (folded into ue)
               float* __restrict__ ue, float* __restrict__ ve,
               const int* __restrict__ eidx, int* __restrict__ deg,
               int* __restrict__ rank)
{
  __shared__ __align__(16) float We[8 * 68];
  __shared__ __align__(16) float Xs[EPB * XSTR2];
  const int tid = threadIdx.x;

  if (blockIdx.x >= PRE_BLOCKS) {
    int e = (blockIdx.x - PRE_BLOCKS) * 256 + tid;
    if (e < NEDGES) rank[e] = atomicAdd(&deg[eidx[e]], 1);   // rank within node
    return;
  }

  for (int t = tid; t < 512; t += 256) We[(t >> 6) * 68 + (t & 63)] = wle[t];
  const int el = tid >> 3, n = tid & 7;
  const int item = blockIdx.x * EPB + el;
  float* X = &Xs[el * XSTR2];
  const bool act = item < NNODES;
  if (act) {
    const float4* ph = (const float4*)(h + (size_t)item * 64 + n * 8);
    *(float4*)&X[n * 8]     = ph[0];
    *(float4*)&X[n * 8 + 4] = ph[1];
  }
  __syncthreads();
  if (!act) return;
  float ua[8], va[8];
  #pragma unroll
  for (int i = 0; i < 8; ++i) { ua[i] = 0.f; va[i] = 0.f; }
  #pragma unroll
  for (int m = 0; m < 8; ++m) {
    const float4 xa = *(const float4*)&X[m * 8];
    const float4 xb = *(const float4*)&X[m * 8 + 4];
    const float4 wa = *(const float4*)&We[n * 68 + m * 4];
    const float4 wb = *(const float4*)&We[n * 68 + (m + 8) * 4];
    ua[0]=fmaf(xa.x,wa.x,ua[0]); ua[1]=fmaf(xa.y,wa.y,ua[1]); ua[2]=fmaf(xa.z,wa.y,ua[2]); ua[3]=fmaf(xa.w,wa.y,ua[3]);
    ua[4]=fmaf(xb.x,wa.z,ua[4]); ua[5]=fmaf(xb.y,wa.z,ua[5]); ua[6]=fmaf(xb.z,wa.z,ua[6]); ua[7]=fmaf(xb.w,wa.w,ua[7]);
    va[0]=fmaf(xa.x,wb.x,va[0]); va[1]=fmaf(xa.y,wb.y,va[1]); va[2]=fmaf(xa.z,wb.y,va[2]); va[3]=fmaf(xa.w,wb.y,va[3]);
    va[4]=fmaf(xb.x,wb.z,va[4]); va[5]=fmaf(xb.y,wb.z,va[5]); va[6]=fmaf(xb.z,wb.z,va[6]); va[7]=fmaf(xb.w,wb.w,va[7]);
  }
  ua[0] += ble[n];   // fold edge bias into ue once per node
  float4* pu = (float4*)(ue + (size_t)item * 64 + n * 8);
  pu[0] = make_float4(ua[0],ua[1],ua[2],ua[3]); pu[1] = make_float4(ua[4],ua[5],ua[6],ua[7]);
  float4* pv = (float4*)(ve + (size_t)item * 64 + n * 8);
  pv[0] = make_float4(va[0],va[1],va[2],va[3]); pv[1] = make_float4(va[4],va[5],va[6],va[7]);
}

// ======================= edge kernel: e-order, slot p = ptr[r]+rank[e] ===================
__global__ __launch_bounds__(256)
void cgenn8_edge(const int* __restrict__ eidx,
                 const int* __restrict__ rank,
                 const int* __restrict__ ptr,
                 const float* __restrict__ ue, const float* __restrict__ ve,
                 _Float16* __restrict__ msgh, WP wp)
{
  __shared__ __align__(16) float Ws[C_TOT];
  __shared__ __align__(16) float Xs[EPB * XSTR2];
  const int tid = threadIdx.x;
  const int el = tid >> 3, n = tid & 7;
  const int e = blockIdx.x * EPB + el;

  // issue gather chain first so it overlaps weight staging
  const int r = eidx[e];
  const int c = eidx[NEDGES + e];
  const int p = ptr[r] + rank[e];          // precomputed CSR slot, no atomic
  const float4* pu = (const float4*)(ue + (size_t)r * 64 + n * 8);
  const float4 u0 = pu[0], u1 = pu[1];
  const float4* pv = (const float4*)(ve + (size_t)c * 64 + n * 8);
  const float4 v0 = pv[0], v1 = pv[1];

  stage_common(tid, Ws, wp);
  __syncthreads();

  float y[8] = { u0.x+v0.x, u0.y+v0.y, u0.z+v0.z, u0.w+v0.w,
                 u1.x+v1.x, u1.y+v1.y, u1.z+v1.z, u1.w+v1.w };  // bias already in ue

  float z[8];
  clifford_tail(&Xs[el * XSTR2], Ws, n, y, z);

  half8 hm;
  hm[0]=(_Float16)z[0]; hm[1]=(_Float16)z[1]; hm[2]=(_Float16)z[2]; hm[3]=(_Float16)z[3];
  hm[4]=(_Float16)z[4]; hm[5]=(_Float16)z[5]; hm[6]=(_Float16)z[6]; hm[7]=(_Float16)z[7];
  *(half8*)(msgh + (size_t)p * 64 + n * 8) = hm;   // one full 128B line per 8-lane group
}

// ======================= node kernel: one wave64 per node, SEQUENTIAL msg reads =========
#define NPB 4   // nodes (waves) per 256-thread block
__global__ __launch_bounds__(256)
void cgenn7_node(const float* __restrict__ h,
                 const _Float16* __restrict__ msgh,
                 const int* __restrict__ ptr,
                 float* __restrict__ out, WP wp)
{
  __shared__ __align__(16) float Ws[CN_TOT];
  __shared__ __align__(16) float Xs[NPB * 132];
  const int tid  = threadIdx.x;
  const int wv   = tid >> 6;          // wave (node) slot in block
  const int slot = (tid >> 3) & 7;    // message stride slot
  const int n    = tid & 7;           // channel
  const int nid  = blockIdx.x * NPB + wv;
  float* X = &Xs[wv * 132];

  stage_common(tid, Ws, wp);
  for (int t = tid; t < 512; t += 256)
    Ws[C_WLIN + (t >> 6) * 68 + (t & 63)] = wp.wlin[t];

  const int beg = ptr[nid], end = ptr[nid + 1];

  // slot-strided sequential aggregation: wave reads 8 consecutive 128B rows per round
  float a[8];
  #pragma unroll
  for (int i = 0; i < 8; ++i) a[i] = 0.f;
  const _Float16* mb = msgh + (size_t)n * 8;
  for (int p = beg + slot; p < end; p += 8) {
    const half8 m = *(const half8*)(mb + (size_t)p * 64);
    #pragma unroll
    for (int i = 0; i < 8; ++i) a[i] += (float)m[i];
  }
  // cross-slot reduce (lanes n, n+8, ..., n+56)
  #pragma unroll
  for (int i = 0; i < 8; ++i) {
    a[i] += __shfl_xor(a[i], 8);
    a[i] += __shfl_xor(a[i], 16);
    a[i] += __shfl_xor(a[i], 32);
  }

  __syncthreads();   // weights staged

  if (slot == 0) {
    float hr[8];
    const float4* ph = (const float4*)(h + (size_t)nid * 64 + n * 8);
    const float4 h0 = ph[0], h1 = ph[1];
    hr[0]=h0.x; hr[1]=h0.y; hr[2]=h0.z; hr[3]=h0.w;
    hr[4]=h1.x; hr[5]=h1.y; hr[6]=h1.z; hr[7]=h1.w;
    *(float4*)&X[n*8]         = h0;
    *(float4*)&X[n*8 + 4]     = h1;
    *(float4*)&X[(8+n)*8]     = make_float4(a[0], a[1], a[2], a[3]);
    *(float4*)&X[(8+n)*8 + 4] = make_float4(a[4], a[5], a[6], a[7]);
    wave_fence();

    // full 16->8 mv_linear
    float y[8];
    #pragma unroll
    for (int i = 0; i < 8; ++i) y[i] = 0.f;
    #pragma unroll
    for (int m = 0; m < 16; ++m) {
      const float4 w4 = *(const float4*)&Ws[C_WLIN + n * 68 + m * 4];
      const float4 xa = *(const float4*)&X[m * 8];
      const float4 xb = *(const float4*)&X[m * 8 + 4];
      y[0]=fmaf(xa.x,w4.x,y[0]); y[1]=fmaf(xa.y,w4.y,y[1]); y[2]=fmaf(xa.z,w4.y,y[2]); y[3]=fmaf(xa.w,w4.y,y[3]);
      y[4]=fmaf(xb.x,w4.z,y[4]); y[5]=fmaf(xb.y,w4.z,y[5]); y[6]=fmaf(xb.z,w4.z,y[6]); y[7]=fmaf(xb.w,w4.w,y[7]);
    }
    y[0] += Ws[C_BLIN + n];

    float z[8];
    clifford_tail(X, Ws, n, y, z);

    float4* po = (float4*)(out + (size_t)nid * 64 + n * 8);
    po[0] = make_float4(hr[0]+z[0], hr[1]+z[1], hr[2]+z[2], hr[3]+z[3]);
    po[1] = make_float4(hr[4]+z[4], hr[5]+z[5], hr[6]+z[6], hr[7]+z[7]);
  }
}

// ======================= MODE0 fallback (atomic path) ================
template<bool IS_NODE>
__global__ __launch_bounds__(256)
void cgenn_block(const float* __restrict__ h,
                 const int* __restrict__ eidx,
                 float* agg_out, WP wp)
{
  __shared__ __align__(16) float Ws[CN_TOT];
  __shared__ __align__(16) float Xs[EPB * 132];
  const int tid = threadIdx.x;
  stage_common(tid, Ws, wp);
  for (int t = tid; t < 512; t += 256)
    Ws[C_WLIN + (t >> 6) * 68 + (t & 63)] = wp.wlin[t];
  const int el = tid >> 3;
  const int n  = tid & 7;
  const int item = blockIdx.x * EPB + el;
  float* X = &Xs[el * 132];
  bool active = true;
  int r = 0;
  float hr[8];
  if (IS_NODE) {
    active = (item < NNODES);
    if (active) {
      const float4* ph = (const float4*)(h + (size_t)item * 64 + n * 8);
      float4 a0 = ph[0], a1 = ph[1];
      hr[0]=a0.x; hr[1]=a0.y; hr[2]=a0.z; hr[3]=a0.w;
      hr[4]=a1.x; hr[5]=a1.y; hr[6]=a1.z; hr[7]=a1.w;
      *(float4*)&X[n*8]     = a0;
      *(float4*)&X[n*8 + 4] = a1;
      const float4* pa = (const float4*)(agg_out + (size_t)item * 64 + n * 8);
      *(float4*)&X[(8+n)*8]     = pa[0];
      *(float4*)&X[(8+n)*8 + 4] = pa[1];
    }
  } else {
    r = eidx[item];
    const int c = eidx[NEDGES + item];
    const float4* ph = (const float4*)(h + (size_t)r * 64 + n * 8);
    float4 a0 = ph[0], a1 = ph[1];
    const float4* pc = (const float4*)(h + (size_t)c * 64 + n * 8);
    float4 b0 = pc[0], b1 = pc[1];
    *(float4*)&X[n*8]       = a0;  *(float4*)&X[n*8 + 4]     = a1;
    *(float4*)&X[(8+n)*8]   = b0;  *(float4*)&X[(8+n)*8 + 4] = b1;
  }
  __syncthreads();
  float y[8];
  #pragma unroll
  for (int i = 0; i < 8; ++i) y[i] = 0.f;
  #pragma unroll
  for (int m = 0; m < 16; ++m) {
    const float4 w4 = *(const float4*)&Ws[C_WLIN + n * 68 + m * 4];
    const float4 xa = *(const float4*)&X[m * 8];
    const float4 xb = *(const float4*)&X[m * 8 + 4];
    y[0]=fmaf(xa.x,w4.x,y[0]); y[1]=fmaf(xa.y,w4.y,y[1]); y[2]=fmaf(xa.z,w4.y,y[2]); y[3]=fmaf(xa.w,w4.y,y[3]);
    y[4]=fmaf(xb.x,w4.z,y[4]); y[5]=fmaf(xb.y,w4.z,y[5]); y[6]=fmaf(xb.z,w4.z,y[6]); y[7]=fmaf(xb.w,w4.w,y[7]);
  }
  y[0] += Ws[C_BLIN + n];
  float z[8];
  clifford_tail(X, Ws, n, y, z);
  if (IS_NODE) {
    if (active) {
      float4* po = (float4*)(agg_out + (size_t)item * 64 + n * 8);
      po[0] = make_float4(hr[0]+z[0], hr[1]+z[1], hr[2]+z[2], hr[3]+z[3]);
      po[1] = make_float4(hr[4]+z[4], hr[5]+z[5], hr[6]+z[6], hr[7]+z[7]);
    }
  } else {
    float* dst = agg_out + (size_t)r * 64 + n * 8;
    #pragma unroll
    for (int i = 0; i < 8; ++i) atomicAdd(dst + i, z[i]);
  }
}

extern "C" void kernel_launch(void* const* d_in, const int* in_sizes, int n_in,
                              void* d_out, int out_size, void* d_ws, size_t ws_size,
                              hipStream_t stream)
{
  (void)in_sizes; (void)n_in; (void)out_size;
  const float* h   = (const float*)d_in[0];
  const int* eidx  = (const int*)d_in[1];
  WP we = { (const float*)d_in[2],  (const float*)d_in[3],  (const float*)d_in[4],
            (const float*)d_in[5],  (const float*)d_in[6],  (const float*)d_in[7],
            (const float*)d_in[8],  (const float*)d_in[9],  (const float*)d_in[10],
            (const float*)d_in[11] };
  WP wn = { (const float*)d_in[12], (const float*)d_in[13], (const float*)d_in[14],
            (const float*)d_in[15], (const float*)d_in[16], (const float*)d_in[17],
            (const float*)d_in[18], (const float*)d_in[19], (const float*)d_in[20],
            (const float*)d_in[21] };
  float* out = (float*)d_out;

  const size_t mhsz   = (size_t)NEDGES * 64 * sizeof(_Float16);   // 51.2 MB
  const size_t nodef  = (size_t)NNODES * 64 * sizeof(float);      // 6.4 MB
  const size_t rksz   = (size_t)NEDGES * sizeof(int);             // 1.6 MB
  const size_t degsz  = (size_t)25008 * sizeof(int);
  const size_t ptrsz  = (size_t)25008 * sizeof(int);
  const size_t need   = mhsz + 2 * nodef + rksz + degsz + ptrsz;  // ~66 MB

  if (ws_size >= need) {
    char* base = (char*)d_ws;
    _Float16* msgh = (_Float16*)base;   base += mhsz;
    float* ue   = (float*)base;         base += nodef;
    float* ve   = (float*)base;         base += nodef;
    int* rank   = (int*)base;           base += rksz;
    int* deg    = (int*)base;           base += degsz;
    int* ptr    = (int*)base;           // NNODES+1 used

    hipMemsetAsync(deg, 0, (NNODES + 1) * sizeof(int), stream);
    pre_count<<<dim3(PRE_BLOCKS + CNT_BLOCKS), dim3(256), 0, stream>>>(
        h, we.wlin, we.blin, ue, ve, eidx, deg, rank);
    csr_scan_fast<<<dim3(1), dim3(1024), 0, stream>>>(deg, ptr);
    cgenn8_edge<<<dim3(NEDGES / EPB), dim3(256), 0, stream>>>(
        eidx, rank, ptr, ue, ve, msgh, we);
    cgenn7_node<<<dim3(NNODES / NPB), dim3(256), 0, stream>>>(h, msgh, ptr, out, wn);
  } else {
    // fallback: atomic aggregation into d_out
    hipMemsetAsync(d_out, 0, (size_t)NNODES * 64 * sizeof(float), stream);
    cgenn_block<false><<<dim3(NEDGES / EPB), dim3(256), 0, stream>>>(h, eidx, out, we);
    cgenn_block<true><<<dim3((NNODES + EPB - 1) / EPB), dim3(256), 0, stream>>>(h, eidx, out, wn);
  }
}